// Round 7
// baseline (6360.130 us; speedup 1.0000x reference)
//
#include <hip/hip_runtime.h>
#include <hip/hip_bf16.h>
#include <stdint.h>

#define T_STEPS 512
#define BATCH   64
#define DIN     512
#define DLAT    1024
#define NWG     256          // 128 col-groups x 2 row-halves = all 256 CUs

typedef __bf16 bf16_t;
typedef __bf16 bf16x4 __attribute__((ext_vector_type(4)));
typedef __bf16 bf16x8 __attribute__((ext_vector_type(8)));
typedef float  f32x4  __attribute__((ext_vector_type(4)));

// ---- workspace layout (bytes) ----
#define XB_OFF    0u                        // bf16 x [512][64][512] = 33,554,432
#define HRING_OFF 33554432u                 // bf16 h ring [2][64][1024] = 262,144
#define CNT_OFF   (HRING_OFF + 262144u)     // int cnt[512][8][16] = 262,144
#define ZERO_BYTES (262144u + 262144u)

// ---- LDS layout (bytes) ----
#define WT_OFF_B   0          // [32 cols][1536 k] bf16, XOR-swizzled = 98,304
#define PART_OFF_B 98304      // f32 [4][32][36] = 18,432
#define PUB_OFF_B  116736     // bf16 [32 rows][8 cols] = 512
#define LDS_BYTES  117248     // forces 1 WG/CU

__global__ void xconv_kernel(const float* __restrict__ x, bf16_t* __restrict__ xb) {
    size_t i = ((size_t)blockIdx.x * 256 + threadIdx.x) * 4;
    const float4 v = *(const float4*)(x + i);
    bf16x4 o;
    o[0] = (bf16_t)v.x; o[1] = (bf16_t)v.y; o[2] = (bf16_t)v.z; o[3] = (bf16_t)v.w;
    *(bf16x4*)(xb + i) = o;
}

__device__ __forceinline__ float rcp_(float x) { return __builtin_amdgcn_rcpf(x); }
__device__ __forceinline__ float sigmoidf_(float v) { return rcp_(1.f + __expf(-v)); }
__device__ __forceinline__ float tanh_fast(float x) {
    const float ax = fabsf(x);
    const float e  = __expf(-2.f * ax);          // v_exp-based, no libm path
    const float t  = (1.f - e) * rcp_(1.f + e);
    return copysignf(t, x);
}

// weight B-fragment from LDS (layout verified R2/R4): lane holds
// W[k = kabs + lq*8 + e][col], byte addr col*3072 + k*2 (^ (col&7)<<4)
__device__ __forceinline__ bf16x8 ldsB(const char* lds, int col, int kabs, int lq) {
    const uint32_t off = (uint32_t)(col * 3072 + kabs * 2 + lq * 16)
                       ^ (uint32_t)((col & 7) << 4);
    return *(const bf16x8*)(lds + WT_OFF_B + off);
}

// device-scope 16B write-through store (publish path: must be visible at MALL)
__device__ __forceinline__ void sth16(bf16_t* p, bf16x8 v) {
    const f32x4 d = __builtin_bit_cast(f32x4, v);
    asm volatile("global_store_dwordx4 %0, %1, off sc1"
                 :: "v"(p), "v"(d) : "memory");
}

__launch_bounds__(256, 1)
__global__ void lstm_main(const float* __restrict__ Wf, const float* __restrict__ Wi,
                          const float* __restrict__ Wo, const float* __restrict__ Wu,
                          const float* __restrict__ bfp, const float* __restrict__ bip,
                          const float* __restrict__ bop, const float* __restrict__ bup,
                          const bf16_t* __restrict__ xb,
                          bf16_t* __restrict__ hring,
                          int* __restrict__ cnt,
                          float* __restrict__ out) {
    extern __shared__ char ldsraw[];
    float*  part = (float*)(ldsraw + PART_OFF_B);   // [4][32 cols][36 rows]
    bf16_t* pub  = (bf16_t*)(ldsraw + PUB_OFF_B);   // [32 rows][8 cols]

    const int tid  = threadIdx.x;
    const int wv   = tid >> 6;       // wave 0..3 = K-slice
    const int lane = tid & 63;
    const int lm   = lane & 15;
    const int lq   = lane >> 4;
    const int cg   = blockIdx.x >> 1;   // col-group 0..127 -> j cols [cg*8, cg*8+8)
    const int rh   = blockIdx.x & 1;    // row half
    const int j0   = cg * 8;
    const int row0 = rh * 32;

    // ---- one-time: weights -> LDS bf16 [32 cols][1536 k], XOR-swizzled ----
    {
        const float* Wgs[4] = {Wf, Wi, Wo, Wu};
        const int gate = wv;            // wave = gate
        const int kr   = lane >> 1;     // 0..31
        const int jh   = lane & 1;      // 0/1: which float4 of the 8 cols
        const float* basep = Wgs[gate] + j0 + jh * 4;
        for (int i = 0; i < 48; ++i) {
            const int k = kr + i * 32;
            const float4 w4 = *(const float4*)(basep + (size_t)k * DLAT);
#pragma unroll
            for (int e = 0; e < 4; ++e) {
                const int c = gate * 8 + jh * 4 + e;
                const uint32_t a = (uint32_t)(c * 3072 + k * 2) ^ (uint32_t)((c & 7) << 4);
                *(bf16_t*)(ldsraw + WT_OFF_B + a) = (bf16_t)(&w4.x)[e];
            }
        }
    }

    // elementwise ownership: one (row, j) per thread; tid = row_l*8 + jp
    const int row_l = tid >> 3;          // 0..31 (local row)
    const int jp    = tid & 7;           // 0..7  (j within group)
    const float bias_r[4] = { bfp[j0 + jp], bip[j0 + jp], bop[j0 + jp], bup[j0 + jp] };
    float cst = 0.f;

    __syncthreads();   // weights visible
    // startup acquire: drop any stale L2 lines of hring left by a previous
    // replay (SDMA memset does not invalidate XCD L2s). Makes cached h
    // loads safe at t=0.
    __builtin_amdgcn_fence(__ATOMIC_ACQUIRE, "agent");

    f32x4 acc[2][2];
#pragma unroll
    for (int rf = 0; rf < 2; ++rf)
#pragma unroll
        for (int cf = 0; cf < 2; ++cf) acc[rf][cf] = (f32x4){0.f, 0.f, 0.f, 0.f};

    // ---- prologue: x_0 GEMM (wave K-slice [wv*128, +128) of DIN) ----
#pragma unroll
    for (int ks = 0; ks < 4; ++ks) {
        const int kx = wv * 128 + ks * 32;
        const bf16x8 a0 = *(const bf16x8*)(xb + (size_t)(row0 + lm) * DIN + kx + lq * 8);
        const bf16x8 a1 = *(const bf16x8*)(xb + (size_t)(row0 + 16 + lm) * DIN + kx + lq * 8);
        const bf16x8 b0 = ldsB(ldsraw, lm,      kx, lq);
        const bf16x8 b1 = ldsB(ldsraw, 16 + lm, kx, lq);
        acc[0][0] = __builtin_amdgcn_mfma_f32_16x16x32_bf16(a0, b0, acc[0][0], 0, 0, 0);
        acc[0][1] = __builtin_amdgcn_mfma_f32_16x16x32_bf16(a0, b1, acc[0][1], 0, 0, 0);
        acc[1][0] = __builtin_amdgcn_mfma_f32_16x16x32_bf16(a1, b0, acc[1][0], 0, 0, 0);
        acc[1][1] = __builtin_amdgcn_mfma_f32_16x16x32_bf16(a1, b1, acc[1][1], 0, 0, 0);
    }

    for (int t = 0; t < T_STEPS; ++t) {
        const bf16_t* hprev = hring + (size_t)(t & 1) * (BATCH * DLAT);
        bf16_t*       hnext = hring + (size_t)((t + 1) & 1) * (BATCH * DLAT);

        // ---- wait for h_t arrivals (cnt[t-1]), then ONE agent-acquire
        // (buffer_inv): L2 drops stale lines, cached h loads fetch fresh
        // data from MALL and get shared across the XCD's 32 CUs ----
        if (t > 0) {
            if (tid == 0) {
                int* cb = cnt + (size_t)(t - 1) * 128;
                int s;
                do {
                    s = 0;
#pragma unroll
                    for (int i = 0; i < 8; ++i)
                        s += __hip_atomic_load(&cb[i * 16], __ATOMIC_RELAXED,
                                               __HIP_MEMORY_SCOPE_AGENT);
                    if (s < NWG) __builtin_amdgcn_s_sleep(1);
                } while (s < NWG);
            }
            __syncthreads();
            __builtin_amdgcn_fence(__ATOMIC_ACQUIRE, "agent");
        }

        // ---- h GEMM: batched cached loads (L2-shared), then one wait,
        // then 32 register MFMAs ----
        {
            const bf16_t* hb0 = hprev + (size_t)(row0 + lm) * DLAT + wv * 256 + lq * 8;
            const bf16_t* hb1 = hb0 + (size_t)16 * DLAT;
            bf16x8 ha0[8], ha1[8];
#pragma unroll
            for (int ks = 0; ks < 8; ++ks) {
                ha0[ks] = *(const bf16x8*)(hb0 + ks * 32);
                ha1[ks] = *(const bf16x8*)(hb1 + ks * 32);
            }
            bf16x8 wb0[8], wb1[8];
#pragma unroll
            for (int ks = 0; ks < 8; ++ks) {
                const int kz = 512 + wv * 256 + ks * 32;
                wb0[ks] = ldsB(ldsraw, lm,      kz, lq);
                wb1[ks] = ldsB(ldsraw, 16 + lm, kz, lq);
            }
#pragma unroll
            for (int ks = 0; ks < 8; ++ks) {
                acc[0][0] = __builtin_amdgcn_mfma_f32_16x16x32_bf16(ha0[ks], wb0[ks], acc[0][0], 0, 0, 0);
                acc[0][1] = __builtin_amdgcn_mfma_f32_16x16x32_bf16(ha0[ks], wb1[ks], acc[0][1], 0, 0, 0);
                acc[1][0] = __builtin_amdgcn_mfma_f32_16x16x32_bf16(ha1[ks], wb0[ks], acc[1][0], 0, 0, 0);
                acc[1][1] = __builtin_amdgcn_mfma_f32_16x16x32_bf16(ha1[ks], wb1[ks], acc[1][1], 0, 0, 0);
            }
        }

        // ---- cross-wave K-reduction via LDS ----
#pragma unroll
        for (int rf = 0; rf < 2; ++rf)
#pragma unroll
            for (int cf = 0; cf < 2; ++cf) {
                const int col = cf * 16 + lm;
                *(f32x4*)&part[(wv * 32 + col) * 36 + rf * 16 + lq * 4] = acc[rf][cf];
            }
        __syncthreads();

        float gs[4];
#pragma unroll
        for (int g = 0; g < 4; ++g) {
            const int col = g * 8 + jp;
            gs[g] = part[(0 * 32 + col) * 36 + row_l] + part[(1 * 32 + col) * 36 + row_l]
                  + part[(2 * 32 + col) * 36 + row_l] + part[(3 * 32 + col) * 36 + row_l]
                  + bias_r[g];
        }
        const float ft = sigmoidf_(gs[0]);
        const float it = sigmoidf_(gs[1]);
        const float ot = sigmoidf_(gs[2]);
        const float ut = tanh_fast(gs[3]);
        cst = ft * cst + it * ut;
        const float hv = ot * tanh_fast(cst);

        // stage h_t tile in LDS (tid = row_l*8 + jp exactly matches layout)
        pub[tid] = (bf16_t)hv;
        __syncthreads();     // pub visible + part reads complete

        // ---- publish h: 32 coalesced 16B write-through stores (wave 0),
        // drain, then arrive on the hierarchical counter ----
        if (tid < 32) {
            const bf16x8 hrow = *(const bf16x8*)(pub + tid * 8);
            sth16(hnext + (size_t)(row0 + tid) * DLAT + j0, hrow);
        }
        if (wv == 0) {
            asm volatile("s_waitcnt vmcnt(0)" ::: "memory");   // h stores at MALL
        }
        if (tid == 0)
            __hip_atomic_fetch_add(&cnt[(size_t)t * 128 + (blockIdx.x & 7) * 16], 1,
                                   __ATOMIC_RELAXED, __HIP_MEMORY_SCOPE_AGENT);

        // out store (cached path) AFTER arrival: off the publish critical chain
        out[(size_t)t * (BATCH * DLAT) + (size_t)(row0 + row_l) * DLAT + j0 + jp] = hv;

        // ---- overlap: x_{t+1} GEMM into fresh acc while others finish ----
#pragma unroll
        for (int rf = 0; rf < 2; ++rf)
#pragma unroll
            for (int cf = 0; cf < 2; ++cf) acc[rf][cf] = (f32x4){0.f, 0.f, 0.f, 0.f};
        if (t + 1 < T_STEPS) {
            const bf16_t* xt = xb + (size_t)(t + 1) * (BATCH * DIN);
#pragma unroll
            for (int ks = 0; ks < 4; ++ks) {
                const int kx = wv * 128 + ks * 32;
                const bf16x8 a0 = *(const bf16x8*)(xt + (size_t)(row0 + lm) * DIN + kx + lq * 8);
                const bf16x8 a1 = *(const bf16x8*)(xt + (size_t)(row0 + 16 + lm) * DIN + kx + lq * 8);
                const bf16x8 b0 = ldsB(ldsraw, lm,      kx, lq);
                const bf16x8 b1 = ldsB(ldsraw, 16 + lm, kx, lq);
                acc[0][0] = __builtin_amdgcn_mfma_f32_16x16x32_bf16(a0, b0, acc[0][0], 0, 0, 0);
                acc[0][1] = __builtin_amdgcn_mfma_f32_16x16x32_bf16(a0, b1, acc[0][1], 0, 0, 0);
                acc[1][0] = __builtin_amdgcn_mfma_f32_16x16x32_bf16(a1, b0, acc[1][0], 0, 0, 0);
                acc[1][1] = __builtin_amdgcn_mfma_f32_16x16x32_bf16(a1, b1, acc[1][1], 0, 0, 0);
            }
        }
    }
}

extern "C" void kernel_launch(void* const* d_in, const int* in_sizes, int n_in,
                              void* d_out, int out_size, void* d_ws, size_t ws_size,
                              hipStream_t stream) {
    const float* x  = (const float*)d_in[0];
    const float* Wf = (const float*)d_in[1];
    const float* Wi = (const float*)d_in[2];
    const float* Wo = (const float*)d_in[3];
    const float* Wu = (const float*)d_in[4];
    const float* bf = (const float*)d_in[5];
    const float* bi = (const float*)d_in[6];
    const float* bo = (const float*)d_in[7];
    const float* bu = (const float*)d_in[8];
    float* out = (float*)d_out;

    char* ws = (char*)d_ws;
    bf16_t* xb    = (bf16_t*)(ws + XB_OFF);
    bf16_t* hring = (bf16_t*)(ws + HRING_OFF);
    int*    cnt   = (int*)(ws + CNT_OFF);

    // zero h ring + step counters (every launch/replay)
    (void)hipMemsetAsync(ws + HRING_OFF, 0, ZERO_BYTES, stream);

    // convert x -> bf16
    xconv_kernel<<<16384, 256, 0, stream>>>(x, xb);

    (void)hipFuncSetAttribute((const void*)lstm_main,
                              hipFuncAttributeMaxDynamicSharedMemorySize, LDS_BYTES);

    lstm_main<<<NWG, 256, LDS_BYTES, stream>>>(Wf, Wi, Wo, Wu, bf, bi, bo, bu,
                                               xb, hring, cnt, out);
}

// Round 8
// 2256.118 us; speedup vs baseline: 2.8191x; 2.8191x over previous
//
#include <hip/hip_runtime.h>
#include <hip/hip_bf16.h>
#include <stdint.h>

#define T_STEPS 512
#define BATCH   64
#define DIN     512
#define DLAT    1024
#define NWG     256          // 128 col-groups x 2 row-halves = all 256 CUs

typedef __bf16 bf16_t;
typedef __bf16 bf16x4 __attribute__((ext_vector_type(4)));
typedef __bf16 bf16x8 __attribute__((ext_vector_type(8)));
typedef float  f32x4  __attribute__((ext_vector_type(4)));
typedef uint32_t u32x4 __attribute__((ext_vector_type(4)));

// ---- workspace layout (bytes) ----
#define XB_OFF     0u                        // bf16 x [512][64][512] = 33,554,432
#define HRING_OFF  33554432u                 // bf16 h ring [2][64][1024] = 262,144
#define FLAGS_OFF  (HRING_OFF + 262144u)     // u32 flags[512][256] = 524,288
#define ZERO_BYTES (262144u + 524288u)

// ---- LDS layout (bytes) ----
#define WT_OFF_B   0          // [32 cols][1536 k] bf16, XOR-swizzled = 98,304
#define PART_OFF_B 98304      // f32 [4][32][36] = 18,432
#define PUB_OFF_B  116736     // bf16 [32 rows][8 cols] = 512
#define LDS_BYTES  117248     // forces 1 WG/CU

__global__ void xconv_kernel(const float* __restrict__ x, bf16_t* __restrict__ xb) {
    size_t i = ((size_t)blockIdx.x * 256 + threadIdx.x) * 4;
    const float4 v = *(const float4*)(x + i);
    bf16x4 o;
    o[0] = (bf16_t)v.x; o[1] = (bf16_t)v.y; o[2] = (bf16_t)v.z; o[3] = (bf16_t)v.w;
    *(bf16x4*)(xb + i) = o;
}

__device__ __forceinline__ float rcp_(float x) { return __builtin_amdgcn_rcpf(x); }
__device__ __forceinline__ float sigmoidf_(float v) { return rcp_(1.f + __expf(-v)); }
__device__ __forceinline__ float tanh_fast(float x) {
    const float ax = fabsf(x);
    const float e  = __expf(-2.f * ax);          // v_exp path, no libm
    const float t  = (1.f - e) * rcp_(1.f + e);
    return copysignf(t, x);
}

// weight B-fragment from LDS (layout verified R2/R4): lane holds
// W[k = kabs + lq*8 + e][col], byte addr col*3072 + k*2 (^ (col&7)<<4)
__device__ __forceinline__ bf16x8 ldsB(const char* lds, int col, int kabs, int lq) {
    const uint32_t off = (uint32_t)(col * 3072 + kabs * 2 + lq * 16)
                       ^ (uint32_t)((col & 7) << 4);
    return *(const bf16x8*)(lds + WT_OFF_B + off);
}

// device-scope (MALL-coherent) 16B load, issued WITHOUT wait.
// Caller must s_waitcnt vmcnt(N) + sched_barrier(0) before consuming.
__device__ __forceinline__ bf16x8 ldh16_issue(const bf16_t* p) {
    f32x4 r;
    asm volatile("global_load_dwordx4 %0, %1, off sc1"
                 : "=v"(r) : "v"(p) : "memory");
    return __builtin_bit_cast(bf16x8, r);
}

// device-scope 16B write-through store
__device__ __forceinline__ void sth16(bf16_t* p, bf16x8 v) {
    const f32x4 d = __builtin_bit_cast(f32x4, v);
    asm volatile("global_store_dwordx4 %0, %1, off sc1"
                 :: "v"(p), "v"(d) : "memory");
}

// flag poll: 16B coherent load with embedded drain
__device__ __forceinline__ u32x4 ldflag4(const uint32_t* p) {
    u32x4 r;
    asm volatile("global_load_dwordx4 %0, %1, off sc1\n\ts_waitcnt vmcnt(0)"
                 : "=v"(r) : "v"(p) : "memory");
    return r;
}

__device__ __forceinline__ void stflag(uint32_t* p, uint32_t v) {
    asm volatile("global_store_dword %0, %1, off sc1" :: "v"(p), "v"(v) : "memory");
}

__launch_bounds__(256, 1)
__global__ void lstm_main(const float* __restrict__ Wf, const float* __restrict__ Wi,
                          const float* __restrict__ Wo, const float* __restrict__ Wu,
                          const float* __restrict__ bfp, const float* __restrict__ bip,
                          const float* __restrict__ bop, const float* __restrict__ bup,
                          const bf16_t* __restrict__ xb,
                          bf16_t* __restrict__ hring,
                          uint32_t* __restrict__ flags,
                          float* __restrict__ out) {
    extern __shared__ char ldsraw[];
    float*  part = (float*)(ldsraw + PART_OFF_B);   // [4][32 cols][36 rows]
    bf16_t* pub  = (bf16_t*)(ldsraw + PUB_OFF_B);   // [32 rows][8 cols]

    const int tid  = threadIdx.x;
    const int wv   = tid >> 6;       // wave 0..3 = K-slice
    const int lane = tid & 63;
    const int lm   = lane & 15;
    const int lq   = lane >> 4;
    const int cg   = blockIdx.x >> 1;   // col-group 0..127 -> j cols [cg*8, cg*8+8)
    const int rh   = blockIdx.x & 1;    // row half
    const int j0   = cg * 8;
    const int row0 = rh * 32;

    // ---- one-time: weights -> LDS bf16 [32 cols][1536 k], XOR-swizzled ----
    {
        const float* Wgs[4] = {Wf, Wi, Wo, Wu};
        const int gate = wv;            // wave = gate
        const int kr   = lane >> 1;     // 0..31
        const int jh   = lane & 1;      // 0/1: which float4 of the 8 cols
        const float* basep = Wgs[gate] + j0 + jh * 4;
        for (int i = 0; i < 48; ++i) {
            const int k = kr + i * 32;
            const float4 w4 = *(const float4*)(basep + (size_t)k * DLAT);
#pragma unroll
            for (int e = 0; e < 4; ++e) {
                const int c = gate * 8 + jh * 4 + e;
                const uint32_t a = (uint32_t)(c * 3072 + k * 2) ^ (uint32_t)((c & 7) << 4);
                *(bf16_t*)(ldsraw + WT_OFF_B + a) = (bf16_t)(&w4.x)[e];
            }
        }
    }

    // elementwise ownership: one (row, j) per thread; tid = row_l*8 + jp
    const int row_l = tid >> 3;          // 0..31 (local row)
    const int jp    = tid & 7;           // 0..7  (j within group)
    const float bias_r[4] = { bfp[j0 + jp], bip[j0 + jp], bop[j0 + jp], bup[j0 + jp] };
    float cst = 0.f;

    __syncthreads();   // weights visible

    f32x4 acc[2][2];
#pragma unroll
    for (int rf = 0; rf < 2; ++rf)
#pragma unroll
        for (int cf = 0; cf < 2; ++cf) acc[rf][cf] = (f32x4){0.f, 0.f, 0.f, 0.f};

    // ---- prologue: x_0 GEMM (wave K-slice [wv*128, +128) of DIN) ----
#pragma unroll
    for (int ks = 0; ks < 4; ++ks) {
        const int kx = wv * 128 + ks * 32;
        const bf16x8 a0 = *(const bf16x8*)(xb + (size_t)(row0 + lm) * DIN + kx + lq * 8);
        const bf16x8 a1 = *(const bf16x8*)(xb + (size_t)(row0 + 16 + lm) * DIN + kx + lq * 8);
        const bf16x8 b0 = ldsB(ldsraw, lm,      kx, lq);
        const bf16x8 b1 = ldsB(ldsraw, 16 + lm, kx, lq);
        acc[0][0] = __builtin_amdgcn_mfma_f32_16x16x32_bf16(a0, b0, acc[0][0], 0, 0, 0);
        acc[0][1] = __builtin_amdgcn_mfma_f32_16x16x32_bf16(a0, b1, acc[0][1], 0, 0, 0);
        acc[1][0] = __builtin_amdgcn_mfma_f32_16x16x32_bf16(a1, b0, acc[1][0], 0, 0, 0);
        acc[1][1] = __builtin_amdgcn_mfma_f32_16x16x32_bf16(a1, b1, acc[1][1], 0, 0, 0);
    }

    for (int t = 0; t < T_STEPS; ++t) {
        const bf16_t* hprev = hring + (size_t)(t & 1) * (BATCH * DLAT);
        bf16_t*       hnext = hring + (size_t)((t + 1) & 1) * (BATCH * DLAT);

        // ---- per-wave poll: all 64 lanes gather all 256 flags of step t-1.
        // No syncthreads: each wave releases itself. hring/flags ride sc1
        // only, so no fences are needed (R6-proven protocol). ----
        if (t > 0) {
            const uint32_t* fp = flags + (size_t)(t - 1) * 256 + lane * 4;
            while (true) {
                const u32x4 v = ldflag4(fp);
                const bool ok = (v.x == 1u) & (v.y == 1u) & (v.z == 1u) & (v.w == 1u);
                if (__all(ok)) break;
                __builtin_amdgcn_s_sleep(1);
            }
            asm volatile("" ::: "memory");
        }

        // ---- h GEMM: issue 16 coherent loads (ks-pair order), prefetch
        // B-frags, then two-stage vmcnt so ks0-3 MFMAs overlap the tail ----
        {
            const bf16_t* hb0 = hprev + (size_t)(row0 + lm) * DLAT + wv * 256 + lq * 8;
            const bf16_t* hb1 = hb0 + (size_t)16 * DLAT;
            bf16x8 ha0[8], ha1[8];
#pragma unroll
            for (int ks = 0; ks < 8; ++ks) {
                ha0[ks] = ldh16_issue(hb0 + ks * 32);
                ha1[ks] = ldh16_issue(hb1 + ks * 32);
            }
            bf16x8 wb0[8], wb1[8];
#pragma unroll
            for (int ks = 0; ks < 8; ++ks) {
                const int kz = 512 + wv * 256 + ks * 32;
                wb0[ks] = ldsB(ldsraw, lm,      kz, lq);
                wb1[ks] = ldsB(ldsraw, 16 + lm, kz, lq);
            }
            asm volatile("s_waitcnt vmcnt(8)" ::: "memory");   // first 8 loads done
            __builtin_amdgcn_sched_barrier(0);
#pragma unroll
            for (int ks = 0; ks < 4; ++ks) {
                acc[0][0] = __builtin_amdgcn_mfma_f32_16x16x32_bf16(ha0[ks], wb0[ks], acc[0][0], 0, 0, 0);
                acc[0][1] = __builtin_amdgcn_mfma_f32_16x16x32_bf16(ha0[ks], wb1[ks], acc[0][1], 0, 0, 0);
                acc[1][0] = __builtin_amdgcn_mfma_f32_16x16x32_bf16(ha1[ks], wb0[ks], acc[1][0], 0, 0, 0);
                acc[1][1] = __builtin_amdgcn_mfma_f32_16x16x32_bf16(ha1[ks], wb1[ks], acc[1][1], 0, 0, 0);
            }
            asm volatile("s_waitcnt vmcnt(0)" ::: "memory");
            __builtin_amdgcn_sched_barrier(0);
#pragma unroll
            for (int ks = 4; ks < 8; ++ks) {
                acc[0][0] = __builtin_amdgcn_mfma_f32_16x16x32_bf16(ha0[ks], wb0[ks], acc[0][0], 0, 0, 0);
                acc[0][1] = __builtin_amdgcn_mfma_f32_16x16x32_bf16(ha0[ks], wb1[ks], acc[0][1], 0, 0, 0);
                acc[1][0] = __builtin_amdgcn_mfma_f32_16x16x32_bf16(ha1[ks], wb0[ks], acc[1][0], 0, 0, 0);
                acc[1][1] = __builtin_amdgcn_mfma_f32_16x16x32_bf16(ha1[ks], wb1[ks], acc[1][1], 0, 0, 0);
            }
        }

        // ---- cross-wave K-reduction via LDS ----
#pragma unroll
        for (int rf = 0; rf < 2; ++rf)
#pragma unroll
            for (int cf = 0; cf < 2; ++cf) {
                const int col = cf * 16 + lm;
                *(f32x4*)&part[(wv * 32 + col) * 36 + rf * 16 + lq * 4] = acc[rf][cf];
            }
        __syncthreads();   // barrier #1: partials visible

        float gs[4];
#pragma unroll
        for (int g = 0; g < 4; ++g) {
            const int col = g * 8 + jp;
            gs[g] = part[(0 * 32 + col) * 36 + row_l] + part[(1 * 32 + col) * 36 + row_l]
                  + part[(2 * 32 + col) * 36 + row_l] + part[(3 * 32 + col) * 36 + row_l]
                  + bias_r[g];
        }
        const float ft = sigmoidf_(gs[0]);
        const float it = sigmoidf_(gs[1]);
        const float ot = sigmoidf_(gs[2]);
        const float ut = tanh_fast(gs[3]);
        cst = ft * cst + it * ut;
        const float hv = ot * tanh_fast(cst);

        // stage h_t tile in LDS (tid = row_l*8 + jp exactly matches layout)
        pub[tid] = (bf16_t)hv;
        __syncthreads();   // barrier #2: pub visible + part reads complete

        // ---- publish h: 32 coalesced 16B sc1 stores (wave 0), drain,
        // then a single RMW-free flag store ----
        if (tid < 32) {
            const bf16x8 hrow = *(const bf16x8*)(pub + tid * 8);
            sth16(hnext + (size_t)(row0 + tid) * DLAT + j0, hrow);
        }
        if (wv == 0) {
            asm volatile("s_waitcnt vmcnt(0)" ::: "memory");   // h stores at MALL
        }
        if (tid == 0)
            stflag(flags + (size_t)t * 256 + blockIdx.x, 1u);

        // out store (cached path) after the publish chain
        out[(size_t)t * (BATCH * DLAT) + (size_t)(row0 + row_l) * DLAT + j0 + jp] = hv;

        // ---- overlap: x_{t+1} GEMM into fresh acc while others finish ----
#pragma unroll
        for (int rf = 0; rf < 2; ++rf)
#pragma unroll
            for (int cf = 0; cf < 2; ++cf) acc[rf][cf] = (f32x4){0.f, 0.f, 0.f, 0.f};
        if (t + 1 < T_STEPS) {
            const bf16_t* xt = xb + (size_t)(t + 1) * (BATCH * DIN);
#pragma unroll
            for (int ks = 0; ks < 4; ++ks) {
                const int kx = wv * 128 + ks * 32;
                const bf16x8 a0 = *(const bf16x8*)(xt + (size_t)(row0 + lm) * DIN + kx + lq * 8);
                const bf16x8 a1 = *(const bf16x8*)(xt + (size_t)(row0 + 16 + lm) * DIN + kx + lq * 8);
                const bf16x8 b0 = ldsB(ldsraw, lm,      kx, lq);
                const bf16x8 b1 = ldsB(ldsraw, 16 + lm, kx, lq);
                acc[0][0] = __builtin_amdgcn_mfma_f32_16x16x32_bf16(a0, b0, acc[0][0], 0, 0, 0);
                acc[0][1] = __builtin_amdgcn_mfma_f32_16x16x32_bf16(a0, b1, acc[0][1], 0, 0, 0);
                acc[1][0] = __builtin_amdgcn_mfma_f32_16x16x32_bf16(a1, b0, acc[1][0], 0, 0, 0);
                acc[1][1] = __builtin_amdgcn_mfma_f32_16x16x32_bf16(a1, b1, acc[1][1], 0, 0, 0);
            }
        }
    }
}

extern "C" void kernel_launch(void* const* d_in, const int* in_sizes, int n_in,
                              void* d_out, int out_size, void* d_ws, size_t ws_size,
                              hipStream_t stream) {
    const float* x  = (const float*)d_in[0];
    const float* Wf = (const float*)d_in[1];
    const float* Wi = (const float*)d_in[2];
    const float* Wo = (const float*)d_in[3];
    const float* Wu = (const float*)d_in[4];
    const float* bf = (const float*)d_in[5];
    const float* bi = (const float*)d_in[6];
    const float* bo = (const float*)d_in[7];
    const float* bu = (const float*)d_in[8];
    float* out = (float*)d_out;

    char* ws = (char*)d_ws;
    bf16_t*   xb    = (bf16_t*)(ws + XB_OFF);
    bf16_t*   hring = (bf16_t*)(ws + HRING_OFF);
    uint32_t* flags = (uint32_t*)(ws + FLAGS_OFF);

    // zero h ring + flags (every launch/replay)
    (void)hipMemsetAsync(ws + HRING_OFF, 0, ZERO_BYTES, stream);

    // convert x -> bf16
    xconv_kernel<<<16384, 256, 0, stream>>>(x, xb);

    (void)hipFuncSetAttribute((const void*)lstm_main,
                              hipFuncAttributeMaxDynamicSharedMemorySize, LDS_BYTES);

    lstm_main<<<NWG, 256, LDS_BYTES, stream>>>(Wf, Wi, Wo, Wu, bf, bi, bo, bu,
                                               xb, hring, flags, out);
}

// Round 10
// 2015.660 us; speedup vs baseline: 3.1554x; 1.1193x over previous
//
#include <hip/hip_runtime.h>
#include <hip/hip_bf16.h>
#include <stdint.h>

#define T_STEPS 512
#define BATCH   64
#define DIN     512
#define DLAT    1024
#define NWG     256          // 64 col-tiles x 4 row-blocks

typedef __bf16 bf16_t;
typedef __bf16 bf16x4 __attribute__((ext_vector_type(4)));
typedef __bf16 bf16x8 __attribute__((ext_vector_type(8)));
typedef float  f32x4  __attribute__((ext_vector_type(4)));

// ---- workspace layout (bytes) ----
#define XB_OFF     0u                        // bf16 x [512][64][512] = 33,554,432
#define WXT_OFF    33554432u                 // bf16 x-weights frag-ordered = 4,194,304
#define FLAGS_OFF  (WXT_OFF + 4194304u)      // u32 flags[513][256] = 525,312
#define HS_OFF     (FLAGS_OFF + 525312u)     // bf16 h ring [2][64][1024] = 262,144
#define SLOT_ELEMS 65536
#define MEMSET_BYTES (525312u + 262144u)     // flags + both h slots

// ---- LDS layout (bytes) ----
#define HW_OFF_B   0          // h-weights [64 cols][1024 k] bf16, swizzled = 131,072
#define PART_OFF_B 131072     // f32 [4 waves][64 cols][20 rows-pad] = 20,480
#define PUB_OFF_B  151552     // bf16 [16 rows][16 j] = 512
#define LDS_BYTES  152064     // forces 1 WG/CU

__global__ void xconv_kernel(const float* __restrict__ x, bf16_t* __restrict__ xb) {
    size_t i = ((size_t)blockIdx.x * 256 + threadIdx.x) * 4;
    const float4 v = *(const float4*)(x + i);
    bf16x4 o;
    o[0] = (bf16_t)v.x; o[1] = (bf16_t)v.y; o[2] = (bf16_t)v.z; o[3] = (bf16_t)v.w;
    *(bf16x4*)(xb + i) = o;
}

// x-weight prep: wxt frag order. Chunk gid (16B): lane = gid&63, f = gid>>6;
// cf = f&3 (gate), ks = (f>>2)&3, wv = (f>>4)&3, ct = f>>6.
// elem e: W_gate[wv*128+ks*32+(lane>>4)*8+e][ct*16+(lane&15)]
__global__ void wxt_prep(const float* __restrict__ Wf, const float* __restrict__ Wi,
                         const float* __restrict__ Wo, const float* __restrict__ Wu,
                         bf16_t* __restrict__ wxt) {
    const int gid  = blockIdx.x * 256 + threadIdx.x;   // 0..262143
    const int lane = gid & 63;
    const int f    = gid >> 6;
    const int cf   = f & 3;
    const int ks   = (f >> 2) & 3;
    const int wv   = (f >> 4) & 3;
    const int ct   = f >> 6;
    const float* Wg = (cf == 0) ? Wf : (cf == 1) ? Wi : (cf == 2) ? Wo : Wu;
    const int k0 = wv * 128 + ks * 32 + (lane >> 4) * 8;
    const int j  = ct * 16 + (lane & 15);
    bf16x8 v;
#pragma unroll
    for (int e = 0; e < 8; ++e) v[e] = (bf16_t)Wg[(size_t)(k0 + e) * DLAT + j];
    *(bf16x8*)(wxt + (size_t)gid * 8) = v;
}

__device__ __forceinline__ float rcp_(float x) { return __builtin_amdgcn_rcpf(x); }
__device__ __forceinline__ float sigmoidf_(float v) { return rcp_(1.f + __expf(-v)); }
__device__ __forceinline__ float tanh_fast(float x) {
    const float ax = fabsf(x);
    const float e  = __expf(-2.f * ax);
    const float t  = (1.f - e) * rcp_(1.f + e);
    return copysignf(t, x);
}

// h-weight frag from LDS: col c, h-k base kh (lane adds lq*8)
__device__ __forceinline__ bf16x8 ldsHW(const char* lds, int c, int kh, int lq) {
    const uint32_t off = (uint32_t)(c * 2048 + kh * 2 + lq * 16)
                       ^ (uint32_t)((c & 7) << 4);
    return *(const bf16x8*)(lds + HW_OFF_B + off);
}

// sc1 (MALL-coherent) 16B load, issued without wait (h path — PROVEN protocol)
__device__ __forceinline__ bf16x8 ldh16_sc1(const bf16_t* p) {
    f32x4 r;
    asm volatile("global_load_dwordx4 %0, %1, off sc1"
                 : "=v"(r) : "v"(p) : "memory");
    return __builtin_bit_cast(bf16x8, r);
}

// device-scope 16B write-through store (publish)
__device__ __forceinline__ void sth16(bf16_t* p, bf16x8 v) {
    const f32x4 d = __builtin_bit_cast(f32x4, v);
    asm volatile("global_store_dwordx4 %0, %1, off sc1"
                 :: "v"(p), "v"(d) : "memory");
}

__device__ __forceinline__ void stflag(uint32_t* p, uint32_t v) {
    asm volatile("global_store_dword %0, %1, off sc1" :: "v"(p), "v"(v) : "memory");
}

__launch_bounds__(256, 1)
__global__ void lstm_main(const float* __restrict__ Wf, const float* __restrict__ Wi,
                          const float* __restrict__ Wo, const float* __restrict__ Wu,
                          const float* __restrict__ bfp, const float* __restrict__ bip,
                          const float* __restrict__ bop, const float* __restrict__ bup,
                          const bf16_t* __restrict__ xb,
                          const bf16_t* __restrict__ wxt,
                          bf16_t* __restrict__ hslots,
                          uint32_t* __restrict__ flags,
                          float* __restrict__ out) {
    extern __shared__ char ldsraw[];
    float*  part = (float*)(ldsraw + PART_OFF_B);   // [4][64 cols][20 rows]
    bf16_t* pub  = (bf16_t*)(ldsraw + PUB_OFF_B);   // [16 rows][16 j]

    const int tid  = threadIdx.x;
    const int wv   = tid >> 6;       // wave = k-slice
    const int lane = tid & 63;
    const int lm   = lane & 15;
    const int lq   = lane >> 4;
    const int rb   = blockIdx.x & 3;    // row-block: rows [rb*16, +16)
    const int ct   = blockIdx.x >> 2;   // col-tile: j [ct*16, +16), all 4 gates
    const int r0   = rb * 16;
    const int j0   = ct * 16;

    // ---- one-time: h-weights -> LDS [64 cols][1024 k] bf16, swizzled ----
    // col c = gate*16 + jj; source W_gate[512+k][j0+jj]
    {
        const int c    = tid & 63;
        const int gate = c >> 4;
        const int jj   = c & 15;
        const float* Wg = (gate == 0) ? Wf : (gate == 1) ? Wi : (gate == 2) ? Wo : Wu;
        const float* src = Wg + (size_t)512 * DLAT + (j0 + jj);
        for (int kb = tid >> 6; kb < 128; kb += 4) {
            const int k0 = kb * 8;
            bf16x8 v;
#pragma unroll
            for (int e = 0; e < 8; ++e) v[e] = (bf16_t)src[(size_t)(k0 + e) * DLAT];
            const uint32_t a = (uint32_t)(c * 2048 + kb * 16) ^ (uint32_t)((c & 7) << 4);
            *(bf16x8*)(ldsraw + HW_OFF_B + a) = v;
        }
    }

    // elementwise ownership: tid = row_l*16 + jj
    const int row_l = tid >> 4;          // 0..15
    const int jj    = tid & 15;          // 0..15
    const float bias_r[4] = { bfp[j0 + jj], bip[j0 + jj], bop[j0 + jj], bup[j0 + jj] };
    float cst = 0.f;

    // per-wave x-weight base (frag-ordered, cached reads — read-only, safe)
    const bf16_t* wx_base = wxt + (size_t)((ct * 4 + wv) * 16) * 512;

    __syncthreads();   // weights visible

    f32x4 acc[4];
#pragma unroll
    for (int cf = 0; cf < 4; ++cf) acc[cf] = (f32x4){0.f, 0.f, 0.f, 0.f};

    // ---- prologue: x_0 GEMM (wave x-k slice [wv*128, +128)) ----
    {
        const bf16_t* xa = xb + (size_t)(r0 + lm) * DIN + wv * 128 + lq * 8;
#pragma unroll
        for (int ks = 0; ks < 4; ++ks) {
            const bf16x8 a = *(const bf16x8*)(xa + ks * 32);
#pragma unroll
            for (int cf = 0; cf < 4; ++cf) {
                const bf16x8 b = *(const bf16x8*)(wx_base + (ks * 4 + cf) * 512 + lane * 8);
                acc[cf] = __builtin_amdgcn_mfma_f32_16x16x32_bf16(a, b, acc[cf], 0, 0, 0);
            }
        }
    }

    for (int t = 0; t < T_STEPS; ++t) {
        const bf16_t* hprev = hslots + (size_t)(t & 1) * SLOT_ELEMS;
        bf16_t*       hnext = hslots + (size_t)((t + 1) & 1) * SLOT_ELEMS;

        // ---- narrowed poll: this WG reads h rows [r0,+16) only, produced by
        // the 64 WGs with the same rb (bid = lane*4 + rb). Readers of our own
        // h region form exactly this same set, so 2-slot reuse stays safe
        // (a producer's flag follows its reads, R8 argument). ----
        if (t > 0) {
            const uint32_t* fp = flags + (size_t)t * 256 + (uint32_t)(lane * 4 + rb);
            while (true) {
                uint32_t v;
                asm volatile("global_load_dword %0, %1, off sc1\n\ts_waitcnt vmcnt(0)"
                             : "=v"(v) : "v"(fp) : "memory");
                if (__all(v == 1u)) break;
                __builtin_amdgcn_s_sleep(1);
            }
            asm volatile("" ::: "memory");
        } else {
            asm volatile("s_waitcnt vmcnt(0)" ::: "memory");   // clean vmcnt baseline
        }

        // ---- h GEMM: 8 sc1 16B loads (16 rows x 256 k per wave), two-stage
        // vmcnt; B-frags from LDS ----
        {
            const bf16_t* hb = hprev + (size_t)(r0 + lm) * DLAT + wv * 256 + lq * 8;
            bf16x8 ha[8];
#pragma unroll
            for (int ks = 0; ks < 8; ++ks) ha[ks] = ldh16_sc1(hb + ks * 32);
            asm volatile("s_waitcnt vmcnt(4)" ::: "memory");
            __builtin_amdgcn_sched_barrier(0);
#pragma unroll
            for (int ks = 0; ks < 4; ++ks) {
                const int kh = wv * 256 + ks * 32;
#pragma unroll
                for (int cf = 0; cf < 4; ++cf) {
                    const bf16x8 b = ldsHW(ldsraw, cf * 16 + lm, kh, lq);
                    acc[cf] = __builtin_amdgcn_mfma_f32_16x16x32_bf16(ha[ks], b, acc[cf], 0, 0, 0);
                }
            }
            asm volatile("s_waitcnt vmcnt(0)" ::: "memory");
            __builtin_amdgcn_sched_barrier(0);
#pragma unroll
            for (int ks = 4; ks < 8; ++ks) {
                const int kh = wv * 256 + ks * 32;
#pragma unroll
                for (int cf = 0; cf < 4; ++cf) {
                    const bf16x8 b = ldsHW(ldsraw, cf * 16 + lm, kh, lq);
                    acc[cf] = __builtin_amdgcn_mfma_f32_16x16x32_bf16(ha[ks], b, acc[cf], 0, 0, 0);
                }
            }
        }

        // ---- cross-wave K-reduction via LDS ----
        // acc[cf][i] = (row = lq*4+i, col = cf*16+lm)
#pragma unroll
        for (int cf = 0; cf < 4; ++cf)
            *(f32x4*)&part[(wv * 64 + cf * 16 + lm) * 20 + lq * 4] = acc[cf];
        __syncthreads();   // barrier #1

        float gs[4];
#pragma unroll
        for (int g = 0; g < 4; ++g) {
            const int c = g * 16 + jj;
            gs[g] = part[(0 * 64 + c) * 20 + row_l] + part[(1 * 64 + c) * 20 + row_l]
                  + part[(2 * 64 + c) * 20 + row_l] + part[(3 * 64 + c) * 20 + row_l]
                  + bias_r[g];
        }
        const float ft = sigmoidf_(gs[0]);
        const float it = sigmoidf_(gs[1]);
        const float ot = sigmoidf_(gs[2]);
        const float ut = tanh_fast(gs[3]);
        cst = ft * cst + it * ut;
        const float hv = ot * tanh_fast(cst);

        pub[row_l * 16 + jj] = (bf16_t)hv;
        __syncthreads();   // barrier #2: pub visible + part reads complete

        // ---- publish: 16 rows x 32B = 32 lanes x 16B sc1 stores (wave 0) ----
        if (tid < 32) {
            const int r2 = tid >> 1, half = tid & 1;
            const bf16x8 hrow = *(const bf16x8*)(pub + r2 * 16 + half * 8);
            sth16(hnext + (size_t)(r0 + r2) * DLAT + j0 + half * 8, hrow);
        }
        if (wv == 0) {
            asm volatile("s_waitcnt vmcnt(0)" ::: "memory");   // h stores at MALL
        }
        if (tid == 0)
            stflag(flags + (size_t)(t + 1) * 256 + blockIdx.x, 1u);

        // out store (cached path) after the publish chain
        out[((size_t)t * BATCH + r0 + row_l) * DLAT + j0 + jj] = hv;

        // ---- overlap: x_{t+1} GEMM into fresh acc while others finish ----
#pragma unroll
        for (int cf = 0; cf < 4; ++cf) acc[cf] = (f32x4){0.f, 0.f, 0.f, 0.f};
        if (t + 1 < T_STEPS) {
            const bf16_t* xa = xb + (size_t)(t + 1) * (BATCH * DIN)
                             + (size_t)(r0 + lm) * DIN + wv * 128 + lq * 8;
#pragma unroll
            for (int ks = 0; ks < 4; ++ks) {
                const bf16x8 a = *(const bf16x8*)(xa + ks * 32);
#pragma unroll
                for (int cf = 0; cf < 4; ++cf) {
                    const bf16x8 b = *(const bf16x8*)(wx_base + (ks * 4 + cf) * 512 + lane * 8);
                    acc[cf] = __builtin_amdgcn_mfma_f32_16x16x32_bf16(a, b, acc[cf], 0, 0, 0);
                }
            }
        }
    }
}

extern "C" void kernel_launch(void* const* d_in, const int* in_sizes, int n_in,
                              void* d_out, int out_size, void* d_ws, size_t ws_size,
                              hipStream_t stream) {
    const float* x  = (const float*)d_in[0];
    const float* Wf = (const float*)d_in[1];
    const float* Wi = (const float*)d_in[2];
    const float* Wo = (const float*)d_in[3];
    const float* Wu = (const float*)d_in[4];
    const float* bf = (const float*)d_in[5];
    const float* bi = (const float*)d_in[6];
    const float* bo = (const float*)d_in[7];
    const float* bu = (const float*)d_in[8];
    float* out = (float*)d_out;

    char* ws = (char*)d_ws;
    bf16_t*   xb     = (bf16_t*)(ws + XB_OFF);
    bf16_t*   wxt    = (bf16_t*)(ws + WXT_OFF);
    uint32_t* flags  = (uint32_t*)(ws + FLAGS_OFF);
    bf16_t*   hslots = (bf16_t*)(ws + HS_OFF);

    // zero flags + both h slots (every launch/replay)
    (void)hipMemsetAsync(ws + FLAGS_OFF, 0, MEMSET_BYTES, stream);

    // convert x -> bf16; transpose x-weights into frag order
    xconv_kernel<<<16384, 256, 0, stream>>>(x, xb);
    wxt_prep<<<1024, 256, 0, stream>>>(Wf, Wi, Wo, Wu, wxt);

    (void)hipFuncSetAttribute((const void*)lstm_main,
                              hipFuncAttributeMaxDynamicSharedMemorySize, LDS_BYTES);

    lstm_main<<<NWG, 256, LDS_BYTES, stream>>>(Wf, Wi, Wo, Wu, bf, bi, bo, bu,
                                               xb, wxt, hslots, flags, out);
}